// Round 17
// baseline (42.544 us; speedup 1.0000x reference)
//
#include <hip/hip_runtime.h>
#include <hip/hip_bf16.h>
#include <math.h>

#define BB 64
#define CC 3
#define HH 384
#define WW 384
#define HW (HH * WW)

// R16: band-pipelined DMA staging. Each block owns one 384x24 band (6 tiles
// of 64x24) of one image. Tile i+1 is staged into the OTHER LDS buffer via
// __builtin_amdgcn_global_load_lds (async, no VGPRs) while tile i is gathered
// from the current buffer. One __syncthreads per tile drains vmcnt (compiler
// emits the vmcnt(0) before s_barrier).
#define TILE_W 64
#define TILE_H 24
#define TX_TILES 6
#define TY_TILES (HH / TILE_H)         // 16
#define NBLOCKS (BB * TY_TILES)        // 1024 (%8==0)

// Rotated bbox of 64x24 at <=15deg: LW <= 71, LH <= 43.
#define LW_STRIDE 71
#define LH_MAX 43
#define NSTG 6
#define LCH (NSTG * 512)   // 3072 >= 43*71=3053, guard-free padded
// LDS = 2 buffers * 3 ch * 3072 * 4 = 73728 B -> 2 blocks/CU x 8w = 16 waves

typedef const __attribute__((address_space(1))) unsigned int* gas_ptr;
typedef __attribute__((address_space(3))) unsigned int* las_ptr;

__global__ __launch_bounds__(512, 4) void GeometricAugment_kernel(
    const float* __restrict__ x,
    const float* __restrict__ angles,
    const float* __restrict__ dx,
    const float* __restrict__ dy,
    float* __restrict__ out) {

    __shared__ float buf0[CC * LCH];
    __shared__ float buf1[CC * LCH];

    // XCD-chunked bijective swizzle (1024 % 8 == 0)
    int bid = blockIdx.x;
    int swz = (bid & 7) * (NBLOCKS / 8) + (bid >> 3);

    int b = swz >> 4;          // image
    int j = swz & 15;          // band

    int tid  = threadIdx.x;
    int tx   = tid & 63;       // 0..63
    int tyl  = tid >> 6;       // 0..7
    int wbase = tid & ~63;     // wave-uniform LDS base offset

    const int Y0 = j * TILE_H;

    const float cx = (WW - 1) * 0.5f;
    const float cy = (HH - 1) * 0.5f;

    float rad = angles[b] * (float)(M_PI / 180.0);
    float si, co;
    __sincosf(rad, &si, &co);
    float txs = dx[b];
    float tys = dy[b];

    // bbox corner extrema for tile 0 (X0=0); shifting X0 by 64:
    //   xs* += 64*co, ys* -= 64*si
    float xo0 = 0.0f - cx - txs;
    float xo1 = (float)(TILE_W - 1) - cx - txs;
    float yo0 = (float)Y0 - cy - tys;
    float yo1 = (float)(Y0 + TILE_H - 1) - cy - tys;

    float xsA = co * xo0 + si * yo0 + cx;
    float xsB = co * xo1 + si * yo0 + cx;
    float xsC = co * xo0 + si * yo1 + cx;
    float xsD = co * xo1 + si * yo1 + cx;
    float ysA = -si * xo0 + co * yo0 + cy;
    float ysB = -si * xo1 + co * yo0 + cy;
    float ysC = -si * xo0 + co * yo1 + cy;
    float ysD = -si * xo1 + co * yo1 + cy;

    float xsmin = fminf(fminf(xsA, xsB), fminf(xsC, xsD));
    float xsmax = fmaxf(fmaxf(xsA, xsB), fmaxf(xsC, xsD));
    float ysmin = fminf(fminf(ysA, ysB), fminf(ysC, ysD));
    float ysmax = fmaxf(fmaxf(ysA, ysB), fmaxf(ysC, ysD));

    const float DXC = 64.0f * co;
    const float DXS = 64.0f * si;

    // per-thread sample coords for tile 0
    float xog = (float)tx - cx - txs;
    float yog = (float)(Y0 + tyl) - cy - tys;
    float xsg =  co * xog + si * yog + cx;
    float ysg = -si * xog + co * yog + cy;
    const float dxs = 8.0f * si;
    const float dys = 8.0f * co;

    const float* imgb = x + (size_t)b * CC * HW;
    float* outbase = out + (size_t)b * CC * HW + (size_t)Y0 * WW + tx;

    // current-tile bbox state
    int  cxi = (int)floorf(xsmin) - 1;
    int  cyi = (int)floorf(ysmin) - 1;
    int  cLH = min((int)floorf(ysmax) + 3 - cyi, LH_MAX);
    bool cInt = (cxi >= 0) && (cyi >= 0) &&
                (cxi + LW_STRIDE <= WW) && (cyi + cLH <= HH);

    // DMA-stage one tile's bbox into dst (guard-free: 6x512 slots, clamped).
    // LDS dest per instr = wave-uniform base + lane*4 (HW rule).
    #define STAGE(dst, XI, YI)                                               \
    {                                                                        \
        _Pragma("unroll")                                                    \
        for (int k = 0; k < NSTG; ++k) {                                     \
            int i  = wbase + k * 512 + tx + ((tyl & 0) << 0);                \
            i = tid + k * 512;                                               \
            int y  = i / LW_STRIDE;                                          \
            int xL = i - y * LW_STRIDE;                                      \
            int gy = min(max((YI) + y, 0), HH - 1);                          \
            int gx = min(max((XI) + xL, 0), WW - 1);                         \
            const float* src = imgb + gy * WW + gx;                          \
            _Pragma("unroll")                                                \
            for (int c = 0; c < CC; ++c) {                                   \
                __builtin_amdgcn_global_load_lds(                            \
                    (gas_ptr)(src + (size_t)c * HW),                         \
                    (las_ptr)((dst) + c * LCH + wbase + k * 512),            \
                    4, 0, 0);                                                \
            }                                                                \
        }                                                                    \
    }

    // prologue: stage tile 0 into buf0
    STAGE(buf0, cxi, cyi);
    __syncthreads();   // drains vmcnt(0) before s_barrier

    #pragma unroll
    for (int it = 0; it < TX_TILES; ++it) {
        float* cbuf = (it & 1) ? buf1 : buf0;
        float* nbuf = (it & 1) ? buf0 : buf1;

        // issue next tile's DMA into the other buffer (overlaps gather)
        int nxi = 0, nyi = 0, nLH = 0;
        bool nInt = false;
        if (it + 1 < TX_TILES) {
            xsmin += DXC; xsmax += DXC;
            ysmin -= DXS; ysmax -= DXS;
            nxi = (int)floorf(xsmin) - 1;
            nyi = (int)floorf(ysmin) - 1;
            nLH = min((int)floorf(ysmax) + 3 - nyi, LH_MAX);
            nInt = (nxi >= 0) && (nyi >= 0) &&
                   (nxi + LW_STRIDE <= WW) && (nyi + nLH <= HH);
            STAGE(nbuf, nxi, nyi);
        }

        // ---- gather current tile from cbuf ----
        float xs = xsg, ys = ysg;
        float* outb = outbase + it * TILE_W;

        if (cInt) {
            #pragma unroll
            for (int r = 0; r < TILE_H / 8; ++r) {
                float x0f = floorf(xs);
                float y0f = floorf(ys);
                float wx = xs - x0f;
                float wy = ys - y0f;
                int base = ((int)y0f - cyi) * LW_STRIDE + ((int)x0f - cxi);

                #pragma unroll
                for (int c = 0; c < CC; ++c) {
                    const float* l = cbuf + c * LCH + base;
                    float v00 = l[0];
                    float v01 = l[1];
                    float v10 = l[LW_STRIDE];
                    float v11 = l[LW_STRIDE + 1];
                    float top = v00 + wx * (v01 - v00);
                    float bot = v10 + wx * (v11 - v10);
                    float v = top + wy * (bot - top);
                    v = fminf(fmaxf(v, 0.0f), 1.0f);
                    __builtin_nontemporal_store(v, outb + (size_t)c * HW + (size_t)(tyl + r * 8) * WW);
                }
                xs += dxs;
                ys += dys;
            }
        } else {
            #pragma unroll
            for (int r = 0; r < TILE_H / 8; ++r) {
                float x0f = floorf(xs);
                float y0f = floorf(ys);
                float wx = xs - x0f;
                float wy = ys - y0f;
                int x0 = (int)x0f;
                int y0 = (int)y0f;
                int x1 = x0 + 1;
                int y1 = y0 + 1;

                float vx0 = (x0 >= 0 && x0 < WW) ? 1.0f : 0.0f;
                float vx1 = (x1 >= 0 && x1 < WW) ? 1.0f : 0.0f;
                float vy0 = (y0 >= 0 && y0 < HH) ? 1.0f : 0.0f;
                float vy1 = (y1 >= 0 && y1 < HH) ? 1.0f : 0.0f;

                float w00 = (1.0f - wx) * (1.0f - wy) * vx0 * vy0;
                float w01 = wx * (1.0f - wy) * vx1 * vy0;
                float w10 = (1.0f - wx) * wy * vx0 * vy1;
                float w11 = wx * wy * vx1 * vy1;

                int base = (y0 - cyi) * LW_STRIDE + (x0 - cxi);

                #pragma unroll
                for (int c = 0; c < CC; ++c) {
                    const float* l = cbuf + c * LCH + base;
                    float v00 = l[0];
                    float v01 = l[1];
                    float v10 = l[LW_STRIDE];
                    float v11 = l[LW_STRIDE + 1];
                    float v = v00 * w00 + v01 * w01 + v10 * w10 + v11 * w11;
                    v = fminf(fmaxf(v, 0.0f), 1.0f);
                    __builtin_nontemporal_store(v, outb + (size_t)c * HW + (size_t)(tyl + r * 8) * WW);
                }
                xs += dxs;
                ys += dys;
            }
        }

        if (it + 1 == TX_TILES) break;
        __syncthreads();   // all gathers of cbuf done + each wave's DMA drained

        cxi = nxi; cyi = nyi; cLH = nLH; cInt = nInt;
        xsg += DXC;
        ysg -= DXS;
    }
    #undef STAGE
}

extern "C" void kernel_launch(void* const* d_in, const int* in_sizes, int n_in,
                              void* d_out, int out_size, void* d_ws, size_t ws_size,
                              hipStream_t stream) {
    const float* x      = (const float*)d_in[0];
    const float* angles = (const float*)d_in[1];
    const float* dx     = (const float*)d_in[2];
    const float* dy     = (const float*)d_in[3];
    float* out = (float*)d_out;

    GeometricAugment_kernel<<<NBLOCKS, 512, 0, stream>>>(x, angles, dx, dy, out);
}

// Round 18
// 38.771 us; speedup vs baseline: 1.0973x; 1.0973x over previous
//
#include <hip/hip_runtime.h>
#include <hip/hip_bf16.h>
#include <math.h>

#define BB 64
#define CC 3
#define HH 384
#define WW 384
#define HW (HH * WW)

// BEST KNOWN (R11, 38.9 us): 64x48 output tile per block, 3 channels, LDS-staged.
// 1024 threads = 64(x) x 16(y); each thread does 3 rows (stride 16).
// Squarer tile -> halo ratio 1.68; full 32-wave occupancy (2 blocks/CU x 16w).
#define TILE_W 64
#define TILE_H 48
#define TX_TILES (WW / TILE_W)                 // 6
#define TY_TILES (HH / TILE_H)                 // 8
#define TILES_PER_IMG (TX_TILES * TY_TILES)    // 48
#define NBLOCKS (BB * TILES_PER_IMG)           // 3072 (divisible by 8)

// Rotated bbox of 64x48 at <=15deg:
//   x floor-span <= 63*cos15+47*sin15 = 73.0 -> 74; +4 -> LW <= 78
//   y floor-span <= 63*sin15+47*cos15 = 61.7 -> 62; +4 -> LH <= 66
#define LW_STRIDE 79      // odd -> rows shift banks by 15
#define LH_MAX 66
#define LCH (LH_MAX * LW_STRIDE)
#define NSTG 6            // ceil(66*79 / 1024) = 6 staging iterations
// LDS = 3 * 66 * 79 * 4 = 62568 B -> 2 blocks/CU x 16 waves = 32 waves (100%)

__global__ __launch_bounds__(1024, 8) void GeometricAugment_kernel(
    const float* __restrict__ x,
    const float* __restrict__ angles,
    const float* __restrict__ dx,
    const float* __restrict__ dy,
    float* __restrict__ out) {

    __shared__ float lds[CC * LCH];

    // XCD-chunked bijective swizzle (3072 % 8 == 0)
    int bid = blockIdx.x;
    int swz = (bid & 7) * (NBLOCKS / 8) + (bid >> 3);

    int b   = swz / TILES_PER_IMG;
    int t   = swz - b * TILES_PER_IMG;
    int tyb = t / TX_TILES;
    int txb = t - tyb * TX_TILES;

    int tid = threadIdx.x;
    int tx  = tid & 63;   // 0..63
    int tyl = tid >> 6;   // 0..15

    const int X0 = txb * TILE_W;
    const int Y0 = tyb * TILE_H;

    const float cx = (WW - 1) * 0.5f;
    const float cy = (HH - 1) * 0.5f;

    float rad = angles[b] * (float)(M_PI / 180.0);
    float si, co;
    __sincosf(rad, &si, &co);
    float txs = dx[b];
    float tys = dy[b];

    // tile-corner sample coords (uniform across block)
    float xo0 = (float)X0 - cx - txs;
    float xo1 = (float)(X0 + TILE_W - 1) - cx - txs;
    float yo0 = (float)Y0 - cy - tys;
    float yo1 = (float)(Y0 + TILE_H - 1) - cy - tys;

    float xsA = co * xo0 + si * yo0 + cx;
    float xsB = co * xo1 + si * yo0 + cx;
    float xsC = co * xo0 + si * yo1 + cx;
    float xsD = co * xo1 + si * yo1 + cx;
    float ysA = -si * xo0 + co * yo0 + cy;
    float ysB = -si * xo1 + co * yo0 + cy;
    float ysC = -si * xo0 + co * yo1 + cy;
    float ysD = -si * xo1 + co * yo1 + cy;

    float xsmin = fminf(fminf(xsA, xsB), fminf(xsC, xsD));
    float xsmax = fmaxf(fmaxf(xsA, xsB), fmaxf(xsC, xsD));
    float ysmin = fminf(fminf(ysA, ysB), fminf(ysC, ysD));
    float ysmax = fmaxf(fmaxf(ysA, ysB), fmaxf(ysC, ysD));

    int ximin = (int)floorf(xsmin) - 1;
    int yimin = (int)floorf(ysmin) - 1;
    int LH = (int)floorf(ysmax) + 2 - yimin + 1;  // <= 66
    LH = min(LH, LH_MAX);

    // block-uniform interior test (full staged window in-bounds)
    bool interior = (ximin >= 0) && (yimin >= 0) &&
                    (ximin + LW_STRIDE <= WW) && (yimin + LH <= HH);

    const float* imgb = x + (size_t)b * CC * HW;

    int nelem = LH * LW_STRIDE;   // <= 5214 <= NSTG*1024

    // ---- stage bbox into LDS ----
    float s0[NSTG], s1[NSTG], s2[NSTG];
    if (interior) {
        const float* srcb = imgb + yimin * WW + ximin;
        #pragma unroll
        for (int k = 0; k < NSTG; ++k) {
            int i = tid + k * 1024;
            if (i < nelem) {
                int y  = i / LW_STRIDE;
                int xL = i - y * LW_STRIDE;
                const float* src = srcb + y * WW + xL;
                s0[k] = src[0];
                s1[k] = src[HW];
                s2[k] = src[2 * HW];
            }
        }
    } else {
        #pragma unroll
        for (int k = 0; k < NSTG; ++k) {
            int i = tid + k * 1024;
            if (i < nelem) {
                int y  = i / LW_STRIDE;
                int xL = i - y * LW_STRIDE;
                int gy = min(max(yimin + y, 0), HH - 1);
                int gx = min(max(ximin + xL, 0), WW - 1);
                const float* src = imgb + gy * WW + gx;
                s0[k] = src[0];
                s1[k] = src[HW];
                s2[k] = src[2 * HW];
            }
        }
    }
    #pragma unroll
    for (int k = 0; k < NSTG; ++k) {
        int i = tid + k * 1024;
        if (i < nelem) {
            lds[i]           = s0[k];
            lds[LCH + i]     = s1[k];
            lds[2 * LCH + i] = s2[k];
        }
    }
    __syncthreads();

    // ---- gather from LDS ----
    int x_out = X0 + tx;
    float xo = (float)x_out - cx - txs;
    float yo = (float)(Y0 + tyl) - cy - tys;

    float xs =  co * xo + si * yo + cx;
    float ys = -si * xo + co * yo + cy;
    const float dxs = 16.0f * si;
    const float dys = 16.0f * co;

    float* outb = out + (size_t)b * CC * HW + (size_t)Y0 * WW + x_out;

    if (interior) {
        #pragma unroll
        for (int r = 0; r < TILE_H / 16; ++r) {
            float x0f = floorf(xs);
            float y0f = floorf(ys);
            float wx = xs - x0f;
            float wy = ys - y0f;
            int base = ((int)y0f - yimin) * LW_STRIDE + ((int)x0f - ximin);

            #pragma unroll
            for (int c = 0; c < CC; ++c) {
                const float* l = lds + c * LCH + base;
                float v00 = l[0];
                float v01 = l[1];
                float v10 = l[LW_STRIDE];
                float v11 = l[LW_STRIDE + 1];
                float top = v00 + wx * (v01 - v00);
                float bot = v10 + wx * (v11 - v10);
                float v = top + wy * (bot - top);
                v = fminf(fmaxf(v, 0.0f), 1.0f);
                __builtin_nontemporal_store(v, outb + (size_t)c * HW + (size_t)(tyl + r * 16) * WW);
            }
            xs += dxs;
            ys += dys;
        }
    } else {
        #pragma unroll
        for (int r = 0; r < TILE_H / 16; ++r) {
            float x0f = floorf(xs);
            float y0f = floorf(ys);
            float wx = xs - x0f;
            float wy = ys - y0f;
            int x0 = (int)x0f;
            int y0 = (int)y0f;
            int x1 = x0 + 1;
            int y1 = y0 + 1;

            float vx0 = (x0 >= 0 && x0 < WW) ? 1.0f : 0.0f;
            float vx1 = (x1 >= 0 && x1 < WW) ? 1.0f : 0.0f;
            float vy0 = (y0 >= 0 && y0 < HH) ? 1.0f : 0.0f;
            float vy1 = (y1 >= 0 && y1 < HH) ? 1.0f : 0.0f;

            float w00 = (1.0f - wx) * (1.0f - wy) * vx0 * vy0;
            float w01 = wx * (1.0f - wy) * vx1 * vy0;
            float w10 = (1.0f - wx) * wy * vx0 * vy1;
            float w11 = wx * wy * vx1 * vy1;

            int base = (y0 - yimin) * LW_STRIDE + (x0 - ximin);

            #pragma unroll
            for (int c = 0; c < CC; ++c) {
                const float* l = lds + c * LCH + base;
                float v00 = l[0];
                float v01 = l[1];
                float v10 = l[LW_STRIDE];
                float v11 = l[LW_STRIDE + 1];
                float v = v00 * w00 + v01 * w01 + v10 * w10 + v11 * w11;
                v = fminf(fmaxf(v, 0.0f), 1.0f);
                __builtin_nontemporal_store(v, outb + (size_t)c * HW + (size_t)(tyl + r * 16) * WW);
            }
            xs += dxs;
            ys += dys;
        }
    }
}

extern "C" void kernel_launch(void* const* d_in, const int* in_sizes, int n_in,
                              void* d_out, int out_size, void* d_ws, size_t ws_size,
                              hipStream_t stream) {
    const float* x      = (const float*)d_in[0];
    const float* angles = (const float*)d_in[1];
    const float* dx     = (const float*)d_in[2];
    const float* dy     = (const float*)d_in[3];
    float* out = (float*)d_out;

    GeometricAugment_kernel<<<NBLOCKS, 1024, 0, stream>>>(x, angles, dx, dy, out);
}